// Round 2
// baseline (270.584 us; speedup 1.0000x reference)
//
#include <hip/hip_runtime.h>
#include <math.h>

#define NN 1024
#define BATCH 32
#define P 8               // pipeline stages (blocks) per batch
#define NB 2              // batches per block (stacked for latency hiding)
#define PAIRS 16          // BATCH / NB
#define NW 4              // waves per sub-batch
#define THREADS 512       // NB * NW * 64
#define DD 32             // diagonals per interval (needs SW >= DD-1, SW+DD <= 65)
#define SW 32             // row stride between waves
#define SPAN 160          // (NW-1)*SW + 64
#define NT 64             // ceil(2047/DD)
#define RB 2              // ring slots per interface (power of 2)
#define GW 0.05f
#define K2 144.2695040888963f            // (1/gamma)*log2(e): scaled domain
#define INV_K2 0.0069314718055994531f    // gamma*ln2
#define BIGS 1.4426950408889634e11f      // 1e9 * K2

#define EXP2F(x) __builtin_amdgcn_exp2f(x)
#define LOG2F(x) __builtin_amdgcn_logf(x)   // v_log_f32 = log2

typedef unsigned long long u64;

// lanes 1..63 <- src[lane-1]; lane 0 <- oldv[0] (DPP wave_shr:1, bound_ctrl=false)
__device__ __forceinline__ float dppshr(float oldv, float src) {
    return __int_as_float(__builtin_amdgcn_update_dpp(
        __float_as_int(oldv), __float_as_int(src), 0x138, 0xF, 0xF, false));
}

// self-validating packet: {f32 value | u32 tag} in one atomic u64
__device__ __forceinline__ u64 pk(float v, unsigned tag) {
    return ((u64)tag << 32) | (u64)__float_as_uint(v);
}

// zero acks[256] + all packet words (tags must not alias across runs)
__global__ __launch_bounds__(256) void ws_init(int* __restrict__ acks,
                                               u64* __restrict__ gx) {
    if (blockIdx.x == 128) acks[threadIdx.x] = 0;
    else gx[(size_t)blockIdx.x * 256 + threadIdx.x] = 0;  // 128*256 = 256*RB*DD*2
}

// Overlapped-band wavefront soft-DTW.
// Round-6: batch-stacking for latency hiding. R1 counters showed 1 wave/SIMD
// (Occupancy 10%) with VALUBusy 46% -> the recurrence chain's latency was
// fully exposed. Now each block hosts NB=2 independent batches (8 waves,
// 2 waves/SIMD); their chains interleave in the issue slots. Weight LUT is
// shared across batches (depends only on |i-j|). Handshake protocol (tagged
// packets, fire-and-forget, LDS-only barrier) unchanged from R1.
__global__ __launch_bounds__(THREADS) void sdtw_pipe8(
        const float* __restrict__ inp, const float* __restrict__ tgt,
        float* __restrict__ partial, int* __restrict__ acks,
        u64* __restrict__ gx)
{
    __shared__ float xs[NB][NN];
    __shared__ float wlblk[3136];    // [guard 544 | O:1024 | E:1024 | guard 544]
    __shared__ float2 exch[NB][2][SPAN];

    const int bid = blockIdx.x;
    const int pair = bid & 15;       // same-pair stages share an XCD (bid%8 = pair%8)
    const int p = bid >> 4;
    const int tid = threadIdx.x;
    const int w = tid >> 6;
    const int s = w >> 2;            // sub-batch within block
    const int v = w & 3;             // wave within sub-batch
    const int lane = tid & 63;
    const int b = pair * NB + s;     // global batch

    // wl2[m] = K2*sigma(G*(|m-1023|-512)), m = j-i+1023 in [0,2046].
    // O[y]=wl2[2y+1] at blk[544+y]; E[y]=wl2[2y] at blk[544+1024+y].
    // Shared by both sub-batches (weight depends only on |i-j|).
    const int b0 = pair * NB;
    for (int tdx = tid; tdx < NN; tdx += THREADS) {
        xs[0][tdx] = inp[b0 * NN + tdx];
        xs[1][tdx] = inp[(b0 + 1) * NN + tdx];
        float mO = (float)(2 * tdx + 1) - 1023.0f;
        float mE = (float)(2 * tdx) - 1023.0f;
        wlblk[544 + tdx]        = K2 / (1.0f + __expf(-GW * (fabsf(mO) - 512.0f)));
        wlblk[544 + 1024 + tdx] = K2 / (1.0f + __expf(-GW * (fabsf(mE) - 512.0f)));
    }

    const float* xsb = xs[s];

    const int i = 128 * p - (DD - 1) + SW * v + lane;   // owned row (may be OOB)
    const int i0 = i - lane;                            // wave's base row
    const bool rowValid = (unsigned)i < (unsigned)NN;
    int ic = min(max(i, 0), NN - 1);
    const float ti = tgt[b * NN + ic];
    const int imask = rowValid ? i : 0x3FFFFFFF;        // forces jj0 very negative
    // wp base: word index 544 + q0, q0 = 16t + 511 - i  (t added per interval)
    const float* wpBase = &wlblk[544 + 511 - i];        // i in [-31,1024] -> idx in [31,1086]

    float r1 = BIGS, r2 = BIGS;             // R(i,k-1), R(i,k-2), scaled by K2
    float dgp = (i == 0) ? 0.0f : BIGS;     // R(i-1,k-2) carry; R(-1,-1)=0
    float bndUp = BIGS;                     // lane-0 'up' feed at interval start
    float xv = 0.0f;                        // x[k - i] rotation register
    int ackC = 0;

    __syncthreads();                        // full sync once: LDS init done

    const int fin = b * P + p;              // inbound interface (p>0)
    const int fout = fin + 1;               // outbound interface (p<P-1)
    u64* gout = gx + (size_t)fout * (RB * DD * 2);
    u64* ginb = gx + (size_t)fin * (RB * DD * 2);

    const bool isProd = (v == NW - 1) && (p < P - 1);
    const bool isCons = (v == 0) && (p > 0);

    u64 pfA = 0, pfB = 0, pfC0 = 0, pfC1 = 0;   // consumer prefetch regs

    for (int t = 0; t < NT; ++t) {
        if (t > 0) {
            // ---- deferred cross-block publish of interval t-1 (tag = t) ----
            // r1/r2 of lanes 31..62 still hold interval t-1 finals here.
            if (isProd) {
                if (t > RB) {                       // slot (t-1)&1 free? need ack >= t-RB
                    while (ackC < t - RB) {
                        __builtin_amdgcn_s_sleep(1);
                        ackC = __hip_atomic_load(&acks[fout], __ATOMIC_RELAXED,
                                                 __HIP_MEMORY_SCOPE_AGENT);
                    }
                }
                if (lane >= DD - 1 && lane < 63) {
                    u64* gq = gout + (size_t)((t - 1) & (RB - 1)) * (DD * 2)
                                   + (size_t)(lane - (DD - 1)) * 2;
                    __hip_atomic_store(&gq[0], pk(r1, (unsigned)t),
                                       __ATOMIC_RELAXED, __HIP_MEMORY_SCOPE_AGENT);
                    __hip_atomic_store(&gq[1], pk(r2, (unsigned)t),
                                       __ATOMIC_RELAXED, __HIP_MEMORY_SCOPE_AGENT);
                }
                // ack prefetch for next gate; latency hides under inner loop
                ackC = __hip_atomic_load(&acks[fout], __ATOMIC_RELAXED,
                                         __HIP_MEMORY_SCOPE_AGENT);
            }
            // ---- refresh stale lanes (0..30) + boundary feed ----
            if (v > 0) {
                const int buf = (t - 1) & 1;
                if (lane < DD - 1) { float2 vv = exch[s][buf][SW * v + lane]; r1 = vv.x; r2 = vv.y; }
                float2 bv = exch[s][buf][SW * v - 1];
                float nd = dppshr(0.0f, r2);
                if (lane == 0)           { bndUp = bv.x; dgp = bv.y; }
                else if (lane <= DD - 2) dgp = nd;
            } else if (p > 0) {
                // consumer: validate prefetched packets; fallback re-poll
                const unsigned expect = (unsigned)t;
                const u64* gslot = ginb + (size_t)((t - 1) & (RB - 1)) * (DD * 2);
                for (;;) {
                    int ok = 1;
                    if (lane < DD - 1)
                        ok = ((unsigned)(pfA >> 32) == expect) &
                             ((unsigned)(pfB >> 32) == expect);
                    if (lane == 0)
                        ok &= ((unsigned)(pfC0 >> 32) == expect) &
                              ((unsigned)(pfC1 >> 32) == expect);
                    if (__all(ok)) break;
                    if (lane < DD - 1) {
                        pfA = __hip_atomic_load((u64*)&gslot[(size_t)(lane + 1) * 2],
                                                __ATOMIC_RELAXED, __HIP_MEMORY_SCOPE_AGENT);
                        pfB = __hip_atomic_load((u64*)&gslot[(size_t)(lane + 1) * 2 + 1],
                                                __ATOMIC_RELAXED, __HIP_MEMORY_SCOPE_AGENT);
                    }
                    if (lane == 0) {
                        pfC0 = __hip_atomic_load((u64*)&gslot[0],
                                                 __ATOMIC_RELAXED, __HIP_MEMORY_SCOPE_AGENT);
                        pfC1 = __hip_atomic_load((u64*)&gslot[1],
                                                 __ATOMIC_RELAXED, __HIP_MEMORY_SCOPE_AGENT);
                    }
                }
                if (lane < DD - 1) { r1 = __uint_as_float((unsigned)pfA);
                                     r2 = __uint_as_float((unsigned)pfB); }
                float nd = dppshr(0.0f, r2);
                if (lane == 0) { bndUp = __uint_as_float((unsigned)pfC0);
                                 dgp   = __uint_as_float((unsigned)pfC1); }
                else if (lane <= DD - 2) dgp = nd;
                // ack value data-depends on loaded tag: cannot precede the loads
                if (lane == 0)
                    __hip_atomic_store(&acks[fin], (int)(pfC0 >> 32),
                                       __ATOMIC_RELAXED, __HIP_MEMORY_SCOPE_AGENT);
            } else {
                bndUp = BIGS;   // p==0, v==0: true boundary
            }
        }

        // ---- interval t compute ----
        const int kbase = t << 5;
        const float* wp = wpBase + (t << 4);            // q0 += 16 per interval
        // re-init x rotation: lane holds x[kbase-1-i] (clamped; garbage-ok when OOB)
        int c = kbase - 1 - i;  c = min(max(c, 0), NN - 1);
        xv = xsb[c];
        // uniform d=0 feed for lane 0: x[kbase - i0]
        int c0 = kbase - i0;    c0 = min(max(c0, 0), NN - 1);
        const float xf0 = xsb[c0];
        const int jj0 = kbase - imask;                  // j at d=0 (or very negative)

        #pragma unroll
        for (int d = 0; d < DD; ++d) {
            xv = dppshr((d == 0) ? xf0 : xv, xv);       // x[k-i] flows diagonally
            const float up = dppshr((d == 0) ? bndUp : r1, r1);   // R(i-1,k-1)
            const float dg = dgp;
            const float left = r1;
            const float wv = (d & 1) ? wp[1024 + ((d + 1) >> 1)]  // E[q0+(d+1)/2]
                                     : wp[(d >> 1)];              // O[q0+d/2]
            const float diff = ti - xv;
            const float dk = diff * diff * wv;          // K2-scaled cost
            const float mn = fminf(fminf(dg, up), left);
            const float md = __builtin_amdgcn_fmed3f(dg, up, left);
            const float mx = fmaxf(fmaxf(dg, up), left);
            const float ss = 1.0f + EXP2F(mn - md) + EXP2F(mn - mx);
            float r = dk + mn - LOG2F(ss);
            r = (jj0 >= -d) ? r : BIGS;                 // entry-side mask only
            r2 = r1; r1 = r; dgp = up;
        }
        if (t == NT - 1) break;

        // intra-block publish: fresh lanes only (wave NW-1's slots are unread)
        if (v < NW - 1 && lane >= DD - 1)
            exch[s][t & 1][SW * v + lane] = make_float2(r1, r2);

        // consumer prefetch for next boundary (tag t+1, slot t&1): issued
        // pre-barrier so fabric latency overlaps barrier-wait + next inner loop
        if (isCons) {
            const u64* gslot = ginb + (size_t)(t & (RB - 1)) * (DD * 2);
            if (lane < DD - 1) {
                pfA = __hip_atomic_load((u64*)&gslot[(size_t)(lane + 1) * 2],
                                        __ATOMIC_RELAXED, __HIP_MEMORY_SCOPE_AGENT);
                pfB = __hip_atomic_load((u64*)&gslot[(size_t)(lane + 1) * 2 + 1],
                                        __ATOMIC_RELAXED, __HIP_MEMORY_SCOPE_AGENT);
            }
            if (lane == 0) {
                pfC0 = __hip_atomic_load((u64*)&gslot[0],
                                         __ATOMIC_RELAXED, __HIP_MEMORY_SCOPE_AGENT);
                pfC1 = __hip_atomic_load((u64*)&gslot[1],
                                         __ATOMIC_RELAXED, __HIP_MEMORY_SCOPE_AGENT);
            }
        }

        // LDS-only barrier: drain ds_writes, leave global ops in flight.
        // memory-clobber asms + sched_barrier pin compiler motion across it.
        asm volatile("s_waitcnt lgkmcnt(0)" ::: "memory");
        __builtin_amdgcn_s_barrier();
        asm volatile("" ::: "memory");
        __builtin_amdgcn_sched_barrier(0);
    }

    // after t=NT-1: r2 = R(i, 2046); cell (1023,1023) is at i=1023 (p=7,v=3,lane=62)
    if (i == NN - 1) partial[b] = r2 * INV_K2;
}

__global__ __launch_bounds__(64) void reduce_mean32(const float* __restrict__ partial,
                                                    float* __restrict__ out) {
    float v = (threadIdx.x < BATCH) ? partial[threadIdx.x] : 0.0f;
    #pragma unroll
    for (int off = 32; off > 0; off >>= 1) v += __shfl_down(v, off);
    if (threadIdx.x == 0) out[0] = v * (1.0f / (float)BATCH);
}

extern "C" void kernel_launch(void* const* d_in, const int* in_sizes, int n_in,
                              void* d_out, int out_size, void* d_ws, size_t ws_size,
                              hipStream_t stream) {
    const float* inp = (const float*)d_in[0];  // [B, N, 1]
    const float* tgt = (const float*)d_in[1];  // [B, N, 1]
    float* out = (float*)d_out;                // [1]

    float* partial = (float*)d_ws;                        // 32 floats
    int* acks  = (int*)((char*)d_ws + 128);               // 256 ints
    u64* gx    = (u64*)((char*)d_ws + 2048);              // 256*RB*DD*2 u64 = 256KB

    ws_init<<<129, 256, 0, stream>>>(acks, gx);
    sdtw_pipe8<<<PAIRS * P, THREADS, 0, stream>>>(inp, tgt, partial, acks, gx);
    reduce_mean32<<<1, 64, 0, stream>>>(partial, out);
}

// Round 3
// 205.290 us; speedup vs baseline: 1.3181x; 1.3181x over previous
//
#include <hip/hip_runtime.h>
#include <math.h>

#define NN 1024
#define BATCH 32
#define P 8               // blocks per batch
#define NW 4              // waves per block
#define THREADS 256
#define DD 32             // diagonals per interval (needs SW >= DD-1, SW+DD <= 65)
#define SW 32             // row stride between waves
#define SPAN 160          // (NW-1)*SW + 64
#define NT 64             // ceil(2047/DD)
#define RB 2              // ring slots per interface (power of 2)
#define WLN 2368          // per-block unified weight LUT length (covers m-range + guards)
#define GW 0.05f
#define K2 144.2695040888963f            // (1/gamma)*log2(e): scaled domain
#define INV_K2 0.0069314718055994531f    // gamma*ln2
#define BIGS 1.4426950408889634e11f      // 1e9 * K2

#define EXP2F(x) __builtin_amdgcn_exp2f(x)
#define LOG2F(x) __builtin_amdgcn_logf(x)   // v_log_f32 = log2

typedef unsigned long long u64;

// lanes 1..63 <- src[lane-1]; lane 0 <- oldv[0] (DPP wave_shr:1, bound_ctrl=false)
__device__ __forceinline__ float dppshr(float oldv, float src) {
    return __int_as_float(__builtin_amdgcn_update_dpp(
        __float_as_int(oldv), __float_as_int(src), 0x138, 0xF, 0xF, false));
}

// self-validating packet: {f32 value | u32 tag} in one atomic u64
__device__ __forceinline__ u64 pk(float v, unsigned tag) {
    return ((u64)tag << 32) | (u64)__float_as_uint(v);
}

// zero acks[256] + all packet words (tags must not alias across runs)
__global__ __launch_bounds__(256) void ws_init(int* __restrict__ acks,
                                               u64* __restrict__ gx) {
    if (blockIdx.x == 128) acks[threadIdx.x] = 0;
    else gx[(size_t)blockIdx.x * 256 + threadIdx.x] = 0;  // 128*256 = 256*RB*DD*2
}

// One DP step. DOMASK is compile-time 0/1; entry mask doubles as the i<0
// boundary (R(-1,j)=inf), so the wave containing rows i<0 keeps it forever.
#define STEPBODY(d, DOMASK) do {                                              \
        xv = dppshr(((d) == 0) ? xf0 : xv, xv);     /* x[k-i] flows diag */   \
        const float up = dppshr(((d) == 0) ? bndUp : r1, r1); /* R(i-1,k-1)*/ \
        const float dg = dgp;                                                 \
        const float left = r1;                                                \
        const float diff = ti - xv;                                           \
        const float dk = diff * diff * wreg[(d)];   /* K2-scaled cost */      \
        const float mn = fminf(fminf(dg, up), left);                          \
        const float md = __builtin_amdgcn_fmed3f(dg, up, left);               \
        const float mx = fmaxf(fmaxf(dg, up), left);                          \
        const float ss = 1.0f + EXP2F(mn - md) + EXP2F(mn - mx);              \
        float r = dk + mn - LOG2F(ss);                                        \
        if (DOMASK) r = (jj0 >= -(d)) ? r : BIGS;   /* entry-side mask */     \
        r2 = r1; r1 = r; dgp = up;                                            \
    } while (0)

// Overlapped-band wavefront soft-DTW, 8 CUs per batch.
// Round-7: R1 structure (256 blocks x 256 thr) + register-file fixes.
// R1 ran at VGPR_Count=20 -> compiler couldn't hoist the 32 per-step LDS
// weight reads (exposed ~120cy each on the serial chain) and recycled store
// temps (vmcnt drains on the producer path). Now: unified per-block weight
// LUT (m = k-2i+1023 is consecutive in d) preloaded 16x ds_read_b64 into a
// full-unrolled register array; ping-pong prefetch of xv/xf0; entry/steady
// inner-loop split (drops cndmask from the chain once all lanes entered).
__global__ __launch_bounds__(THREADS) void sdtw_pipe8(
        const float* __restrict__ inp, const float* __restrict__ tgt,
        float* __restrict__ partial, int* __restrict__ acks,
        u64* __restrict__ gx)
{
    __shared__ __align__(16) float xs[NN];
    __shared__ __align__(16) float wlu[WLN];
    __shared__ float2 exch[2][SPAN];

    const int bid = blockIdx.x;
    const int b = bid & 31;          // same-batch stages share an XCD (bid%8 = b%8)
    const int p = bid >> 5;
    const int tid = threadIdx.x;
    const int w = tid >> 6;
    const int lane = tid & 63;

    // unified LUT: wlu[idx] = K2*sigma(G*(|m-1023|-512)), m = idx + mlo.
    // Per-block m range: m = k - 2i + 1023, k in [0,2047], i in [128p-31,128p+128]
    // -> [767-256p, 3132-256p]; out-of-range m only feeds masked/unread cells
    // (finite benign value K2). mlo odd + m0 odd -> idx even -> 8B aligned.
    const int mlo = 767 - 256 * p;
    for (int tdx = tid; tdx < NN; tdx += THREADS)
        xs[tdx] = inp[b * NN + tdx];
    for (int tdx = tid; tdx < WLN; tdx += THREADS) {
        int m = tdx + mlo;
        float val = K2;
        if ((unsigned)m <= 2046u)
            val = K2 / (1.0f + __expf(-GW * (fabsf((float)m - 1023.0f) - 512.0f)));
        wlu[tdx] = val;
    }

    const int i = 128 * p - (DD - 1) + SW * w + lane;   // owned row (may be OOB)
    const int i0 = i - lane;                            // wave's base row
    const bool rowValid = (unsigned)i < (unsigned)NN;
    int ic = min(max(i, 0), NN - 1);
    const float ti = tgt[b * NN + ic];
    const int imask = rowValid ? i : 0x3FFFFFFF;        // forces jj0 very negative
    // weight index at step d: (t<<5) + wq + d, wq = 256 + 256p - 2i (even, in [0,318])
    const int wq = 256 + 256 * p - 2 * i;

    float r1 = BIGS, r2 = BIGS;             // R(i,k-1), R(i,k-2), scaled by K2
    float dgp = (i == 0) ? 0.0f : BIGS;     // R(i-1,k-2) carry; R(-1,-1)=0
    float bndUp = BIGS;                     // lane-0 'up' feed at interval start
    float xv = 0.0f;                        // x[k - i] rotation register
    int ackC = 0;

    __syncthreads();                        // full sync once: LDS init done

    const int fin = b * P + p;              // inbound interface (p>0)
    const int fout = fin + 1;               // outbound interface (p<P-1)
    u64* gout = gx + (size_t)fout * (RB * DD * 2);
    u64* ginb = gx + (size_t)fin * (RB * DD * 2);

    const bool isProd = (w == NW - 1) && (p < P - 1);
    const bool isCons = (w == 0) && (p > 0);

    u64 pfA = 0, pfB = 0, pfC0 = 0, pfC1 = 0;   // consumer prefetch regs

    // ping-pong prefetch of the x rotation seeds for interval t=0
    int cP  = min(max(-1 - i, 0), NN - 1);
    int c0P = min(max(-i0, 0), NN - 1);
    float xpreA = xs[cP];       // -> xv init: x[kbase-1-i]
    float xpreB = xs[c0P];      // -> xf0:     x[kbase-i0]

    for (int t = 0; t < NT; ++t) {
        if (t > 0) {
            // ---- deferred cross-block publish of interval t-1 (tag = t) ----
            // r1/r2 of lanes 31..62 still hold interval t-1 finals here.
            if (isProd) {
                if (t > RB) {                       // slot (t-1)&1 free? need ack >= t-RB
                    while (ackC < t - RB) {
                        __builtin_amdgcn_s_sleep(1);
                        ackC = __hip_atomic_load(&acks[fout], __ATOMIC_RELAXED,
                                                 __HIP_MEMORY_SCOPE_AGENT);
                    }
                }
                if (lane >= DD - 1 && lane < 63) {
                    u64* gq = gout + (size_t)((t - 1) & (RB - 1)) * (DD * 2)
                                   + (size_t)(lane - (DD - 1)) * 2;
                    __hip_atomic_store(&gq[0], pk(r1, (unsigned)t),
                                       __ATOMIC_RELAXED, __HIP_MEMORY_SCOPE_AGENT);
                    __hip_atomic_store(&gq[1], pk(r2, (unsigned)t),
                                       __ATOMIC_RELAXED, __HIP_MEMORY_SCOPE_AGENT);
                }
                // ack prefetch for next gate; latency hides under inner loop
                ackC = __hip_atomic_load(&acks[fout], __ATOMIC_RELAXED,
                                         __HIP_MEMORY_SCOPE_AGENT);
            }
            // ---- refresh stale lanes (0..30) + boundary feed ----
            if (w > 0) {
                const int buf = (t - 1) & 1;
                if (lane < DD - 1) { float2 vv = exch[buf][SW * w + lane]; r1 = vv.x; r2 = vv.y; }
                float2 bv = exch[buf][SW * w - 1];
                float nd = dppshr(0.0f, r2);
                if (lane == 0)           { bndUp = bv.x; dgp = bv.y; }
                else if (lane <= DD - 2) dgp = nd;
            } else if (p > 0) {
                // consumer: validate prefetched packets; fallback re-poll
                const unsigned expect = (unsigned)t;
                const u64* gslot = ginb + (size_t)((t - 1) & (RB - 1)) * (DD * 2);
                for (;;) {
                    int ok = 1;
                    if (lane < DD - 1)
                        ok = ((unsigned)(pfA >> 32) == expect) &
                             ((unsigned)(pfB >> 32) == expect);
                    if (lane == 0)
                        ok &= ((unsigned)(pfC0 >> 32) == expect) &
                              ((unsigned)(pfC1 >> 32) == expect);
                    if (__all(ok)) break;
                    if (lane < DD - 1) {
                        pfA = __hip_atomic_load((u64*)&gslot[(size_t)(lane + 1) * 2],
                                                __ATOMIC_RELAXED, __HIP_MEMORY_SCOPE_AGENT);
                        pfB = __hip_atomic_load((u64*)&gslot[(size_t)(lane + 1) * 2 + 1],
                                                __ATOMIC_RELAXED, __HIP_MEMORY_SCOPE_AGENT);
                    }
                    if (lane == 0) {
                        pfC0 = __hip_atomic_load((u64*)&gslot[0],
                                                 __ATOMIC_RELAXED, __HIP_MEMORY_SCOPE_AGENT);
                        pfC1 = __hip_atomic_load((u64*)&gslot[1],
                                                 __ATOMIC_RELAXED, __HIP_MEMORY_SCOPE_AGENT);
                    }
                }
                if (lane < DD - 1) { r1 = __uint_as_float((unsigned)pfA);
                                     r2 = __uint_as_float((unsigned)pfB); }
                float nd = dppshr(0.0f, r2);
                if (lane == 0) { bndUp = __uint_as_float((unsigned)pfC0);
                                 dgp   = __uint_as_float((unsigned)pfC1); }
                else if (lane <= DD - 2) dgp = nd;
                // ack value data-depends on loaded tag: cannot precede the loads
                if (lane == 0)
                    __hip_atomic_store(&acks[fin], (int)(pfC0 >> 32),
                                       __ATOMIC_RELAXED, __HIP_MEMORY_SCOPE_AGENT);
            } else {
                bndUp = BIGS;   // p==0, w==0: true boundary
            }
        }

        // ---- interval t compute ----
        const int kbase = t << 5;
        const int jj0 = kbase - imask;                  // j at d=0 (or very negative)

        // preload this interval's 32 consecutive weights into registers
        // (16x ds_read_b64; removes per-step LDS latency from the chain)
        const float* wp = &wlu[kbase + wq];
        float wreg[DD];
        #pragma unroll
        for (int h = 0; h < DD / 2; ++h) {
            float2 w2 = *reinterpret_cast<const float2*>(&wp[2 * h]);
            wreg[2 * h] = w2.x; wreg[2 * h + 1] = w2.y;
        }

        const float xf0 = xpreB;
        xv = xpreA;
        // issue next interval's x seeds now; full interval to complete
        { int cN  = min(max(kbase + DD - 1 - i, 0), NN - 1);
          int c0N = min(max(kbase + DD - i0, 0), NN - 1);
          xpreA = xs[cN]; xpreB = xs[c0N]; }

        if (i0 >= 0 && kbase >= i0 + 63) {
            // steady: every lane has j>=0 for all d; rows >1023 compute
            // garbage that is provably never consumed (dpp feeds upward only,
            // exch/cross-block publishes cover valid rows only)
            #pragma unroll
            for (int d = 0; d < DD; ++d) STEPBODY(d, 0);
        } else {
            #pragma unroll
            for (int d = 0; d < DD; ++d) STEPBODY(d, 1);
        }
        if (t == NT - 1) break;

        // intra-block publish: fresh lanes only (wave NW-1's slots are unread)
        if (w < NW - 1 && lane >= DD - 1)
            exch[t & 1][SW * w + lane] = make_float2(r1, r2);

        // consumer prefetch for next boundary (tag t+1, slot t&1): issued
        // pre-barrier so fabric latency overlaps barrier-wait + next refresh
        if (isCons) {
            const u64* gslot = ginb + (size_t)(t & (RB - 1)) * (DD * 2);
            if (lane < DD - 1) {
                pfA = __hip_atomic_load((u64*)&gslot[(size_t)(lane + 1) * 2],
                                        __ATOMIC_RELAXED, __HIP_MEMORY_SCOPE_AGENT);
                pfB = __hip_atomic_load((u64*)&gslot[(size_t)(lane + 1) * 2 + 1],
                                        __ATOMIC_RELAXED, __HIP_MEMORY_SCOPE_AGENT);
            }
            if (lane == 0) {
                pfC0 = __hip_atomic_load((u64*)&gslot[0],
                                         __ATOMIC_RELAXED, __HIP_MEMORY_SCOPE_AGENT);
                pfC1 = __hip_atomic_load((u64*)&gslot[1],
                                         __ATOMIC_RELAXED, __HIP_MEMORY_SCOPE_AGENT);
            }
        }

        // LDS-only barrier: drain ds_writes, leave global ops in flight.
        asm volatile("s_waitcnt lgkmcnt(0)" ::: "memory");
        __builtin_amdgcn_s_barrier();
        asm volatile("" ::: "memory");
        __builtin_amdgcn_sched_barrier(0);
    }

    // after t=NT-1: r2 = R(i, 2046); cell (1023,1023) is at i=1023 (p=7,w=3,lane=62)
    if (i == NN - 1) partial[b] = r2 * INV_K2;
}

__global__ __launch_bounds__(64) void reduce_mean32(const float* __restrict__ partial,
                                                    float* __restrict__ out) {
    float v = (threadIdx.x < BATCH) ? partial[threadIdx.x] : 0.0f;
    #pragma unroll
    for (int off = 32; off > 0; off >>= 1) v += __shfl_down(v, off);
    if (threadIdx.x == 0) out[0] = v * (1.0f / (float)BATCH);
}

extern "C" void kernel_launch(void* const* d_in, const int* in_sizes, int n_in,
                              void* d_out, int out_size, void* d_ws, size_t ws_size,
                              hipStream_t stream) {
    const float* inp = (const float*)d_in[0];  // [B, N, 1]
    const float* tgt = (const float*)d_in[1];  // [B, N, 1]
    float* out = (float*)d_out;                // [1]

    float* partial = (float*)d_ws;                        // 32 floats
    int* acks  = (int*)((char*)d_ws + 128);               // 256 ints
    u64* gx    = (u64*)((char*)d_ws + 2048);              // 256*RB*DD*2 u64 = 256KB

    ws_init<<<129, 256, 0, stream>>>(acks, gx);
    sdtw_pipe8<<<BATCH * P, THREADS, 0, stream>>>(inp, tgt, partial, acks, gx);
    reduce_mean32<<<1, 64, 0, stream>>>(partial, out);
}